// Round 5
// baseline (231.308 us; speedup 1.0000x reference)
//
#include <hip/hip_runtime.h>

// out[s,b,d] = x[s,b,d] + (2047.5 - s), shape (4096, 4, 2048) fp32.
// Pure streaming, zero reuse: 268 MB compulsory traffic.
//
// Measured ladder (kernel = metric - 2 poison fills @ ~79.7 us):
//   NT/NT, 4 f4/thread, 8192 one-shot blocks : 58.2 us (4.6 TB/s)  [R0 best]
//   NT/plain                                 : 60.0 us
//   plain/plain                              : 65.4 us
//   NT/NT, 8 f4/thread, 4096 blocks          : 60.1 us  [R4 null]
// Cache-flag and burst-shape levers exhausted; NT/NT optimal (post-poison
// dirty L3 makes any allocating access pay poison writebacks).
//
// R5 change: grid shape. Guideline 11 + the 6.29 TB/s m13 copy ceiling
// use ~2048-block persistent grids; our 8192 one-shot blocks = 32768
// short waves = 4 residency generations of launch/drain churn (each wave
// only 4 loads+4 stores). The 6.7 TB/s fills run at 9.5% occupancy —
// saturation wants few long waves. Now: 2048 blocks x 256 thr = exactly
// 32 waves/CU, ONE generation; 16 float4/thread in 4 groups of 4
// (keeps the proven 4-outstanding-NT-load burst shape).
// Predict kernel 58 -> ~48-52, metric ~208-212. If unchanged: declare
// roofline (all levers measured-null at ~4.6 TB/s mixed-stream).
//
// B*D = 8192 floats per s-row = 2048 float4s => s = i4 >> 11.

typedef float fvec4 __attribute__((ext_vector_type(4)));

#define TOTAL_THREADS (2048 * 256)   // 524288 = n4 / 16

__global__ __launch_bounds__(256) void rpe_kernel(const fvec4* __restrict__ x,
                                                  fvec4* __restrict__ out) {
    int t = blockIdx.x * 256 + threadIdx.x;

    #pragma unroll
    for (int g = 0; g < 4; ++g) {
        fvec4 v[4];
        int idx[4];
        #pragma unroll
        for (int k = 0; k < 4; ++k) {
            idx[k] = t + (g * 4 + k) * TOTAL_THREADS;
            v[k] = __builtin_nontemporal_load(&x[idx[k]]);
        }
        #pragma unroll
        for (int k = 0; k < 4; ++k) {
            float bias = 2047.5f - (float)(idx[k] >> 11);
            v[k] += bias;   // ext_vector: scalar broadcast add
            __builtin_nontemporal_store(v[k], &out[idx[k]]);
        }
    }
}

extern "C" void kernel_launch(void* const* d_in, const int* in_sizes, int n_in,
                              void* d_out, int out_size, void* d_ws, size_t ws_size,
                              hipStream_t stream) {
    const fvec4* x = (const fvec4*)d_in[0];
    fvec4* out = (fvec4*)d_out;
    // n4 = 8,388,608 float4s = 16 per thread at 2048 blocks x 256 threads.
    rpe_kernel<<<2048, 256, 0, stream>>>(x, out);
}

// Round 6
// 217.732 us; speedup vs baseline: 1.0624x; 1.0624x over previous
//
#include <hip/hip_runtime.h>

// out[s,b,d] = x[s,b,d] + (2047.5 - s), shape (4096, 4, 2048) fp32.
// Pure streaming, zero reuse: 268 MB compulsory traffic.
//
// FINAL (R6 = revert to R0, the measured optimum). Full ladder, kernel
// time inferred as metric - 2 poison fills (~79.7 us each):
//   NT/NT, 4 f4/thread, 8192 blocks : 58.2 us (4.6 TB/s)  <- THIS
//   NT load + plain store           : 60.0 us
//   NT/NT, 8 f4/thread, 4096 blocks : 60.1 us  (ILP depth: null)
//   plain/plain                     : 65.4 us  (poison writebacks)
//   NT/NT persistent 2048 blocks    : ~68 us   (grid shape: hurts)
//
// Structural ceiling: the harness writes 1 GB of poison (plain stores,
// 6.7 TB/s fills) right before dispatch, leaving L2/L3 fully dirty.
// NT both ways avoids all poison-writeback traffic; the remaining
// 4.6 TB/s is this box's post-poison mixed r+w stream rate. The metric
// itself is ~160 us of fixed harness fills + ~58 us kernel; no
// kernel-side change can touch the fills. All HIP-level levers
// (cache flags x4, burst depth, grid shape) measured; R0 is optimal.
//
// Layout: 4 float4s/thread, stride-256 interleave (wave = 4x contiguous
// 1KB bursts; block = 16 KB contiguous). s = i4 >> 11 (B*D = 8192 floats
// per s-row = 2048 float4s).

typedef float fvec4 __attribute__((ext_vector_type(4)));

__global__ __launch_bounds__(256) void rpe_kernel(const fvec4* __restrict__ x,
                                                  fvec4* __restrict__ out) {
    int base = blockIdx.x * 1024 + threadIdx.x;

    fvec4 v[4];
    int idx[4];
    #pragma unroll
    for (int k = 0; k < 4; ++k) {
        idx[k] = base + k * 256;
        v[k] = __builtin_nontemporal_load(&x[idx[k]]);
    }
    #pragma unroll
    for (int k = 0; k < 4; ++k) {
        float bias = 2047.5f - (float)(idx[k] >> 11);
        v[k] += bias;   // ext_vector: scalar broadcast add
        __builtin_nontemporal_store(v[k], &out[idx[k]]);
    }
}

extern "C" void kernel_launch(void* const* d_in, const int* in_sizes, int n_in,
                              void* d_out, int out_size, void* d_ws, size_t ws_size,
                              hipStream_t stream) {
    const fvec4* x = (const fvec4*)d_in[0];
    fvec4* out = (fvec4*)d_out;
    int n4 = in_sizes[0] / 4;                 // 8,388,608, divisible by 1024
    int blocks = n4 / 1024;                   // 8192 blocks x 256 threads x 4 float4
    rpe_kernel<<<blocks, 256, 0, stream>>>(x, out);
}